// Round 13
// baseline (972.200 us; speedup 1.0000x reference)
//
#include <hip/hip_runtime.h>

#define D 128
#define NP 65536
#define NV 1024

typedef __attribute__((ext_vector_type(8))) short short8;
typedef __attribute__((ext_vector_type(4))) float f32x4;

__device__ __forceinline__ unsigned short f2bf(float x) {
    unsigned int u = __builtin_bit_cast(unsigned int, x);
    u += 0x7FFFu + ((u >> 16) & 1u);          // round-to-nearest-even
    return (unsigned short)(u >> 16);
}
__device__ __forceinline__ unsigned int pack2bf(float a, float b) {
    return (unsigned int)f2bf(a) | ((unsigned int)f2bf(b) << 16);
}
__device__ __forceinline__ float bflo(unsigned int u) {
    return __builtin_bit_cast(float, u << 16);
}
__device__ __forceinline__ float bfhi(unsigned int u) {
    return __builtin_bit_cast(float, u & 0xFFFF0000u);
}
__device__ __forceinline__ short8 ntld8h(const unsigned short* p) {
    return __builtin_nontemporal_load((const short8*)p);
}
__device__ __forceinline__ void ntst(float* p, float v) {
    __builtin_nontemporal_store(v, p);
}

// ---------------- weight prep: W[k][n] f32 -> Wt[n][k] bf16 ----------------
__global__ __launch_bounds__(256)
void k_prep(const float* __restrict__ Wsp, const float* __restrict__ Wvw,
            const float* __restrict__ Wgl, const float* __restrict__ Wpr,
            unsigned short* __restrict__ o)
{
    const float* W = (blockIdx.x == 0) ? Wsp : (blockIdx.x == 1) ? Wvw
                   : (blockIdx.x == 2) ? Wgl : Wpr;
    unsigned short* Wt = o + (size_t)blockIdx.x * 16384;
    for (int c = threadIdx.x; c < 2048; c += 256) {
        int n = c >> 4, kb = (c & 15) * 8;
        unsigned int p[4];
        #pragma unroll
        for (int j = 0; j < 4; ++j)
            p[j] = pack2bf(W[(kb + 2 * j) * D + n], W[(kb + 2 * j + 1) * D + n]);
        *(short8*)(Wt + n * 128 + kb) = *(short8*)p;
    }
}

// ---------------- fused: f32 -> bf16 entry-order copy (4-way ILP) + count histogram ----------------
__global__ __launch_bounds__(256)
void k_cvt_count(const float* __restrict__ values, const int* __restrict__ vi,
                 const int* __restrict__ pi, int* __restrict__ cp, int* __restrict__ cv,
                 uint4* __restrict__ ebuf4, int nnz)
{
    int tid = blockIdx.x * 256 + threadIdx.x;
    int nthreads = gridDim.x * 256;
    for (int e = tid; e < nnz; e += nthreads) {
        atomicAdd(&cp[pi[e]], 1);
        atomicAdd(&cv[vi[e]], 1);
    }
    // copy: nnz*16 uint4 chunks; 4 independent chunks per thread per iteration.
    // Block covers a contiguous 1024-chunk (32 KB) window: lane t handles
    // t, t+256, t+512, t+768 — coalesced within each quarter, 4 loads in flight.
    size_t total = (size_t)nnz * 16;
    size_t step = (size_t)nthreads * 4;
    for (size_t base = (size_t)blockIdx.x * 1024; base < total; base += step) {
        size_t i0 = base + threadIdx.x;
        f32x4 a[4], b[4];
        #pragma unroll
        for (int q = 0; q < 4; ++q) {
            size_t i = i0 + (size_t)q * 256;
            if (i < total) {
                const float* src = values + i * 8;
                a[q] = *(const f32x4*)src;
                b[q] = *(const f32x4*)(src + 4);
            }
        }
        #pragma unroll
        for (int q = 0; q < 4; ++q) {
            size_t i = i0 + (size_t)q * 256;
            if (i < total) {
                uint4 o;
                o.x = pack2bf(a[q][0], a[q][1]); o.y = pack2bf(a[q][2], a[q][3]);
                o.z = pack2bf(b[q][0], b[q][1]); o.w = pack2bf(b[q][2], b[q][3]);
                ebuf4[i] = o;
            }
        }
    }
}

// ---------------- scans ----------------
__global__ __launch_bounds__(256)
void k_scanA(const int* __restrict__ cp, int* __restrict__ bsum)
{
    __shared__ int l[256];
    int t = threadIdx.x;
    int4 c = ((const int4*)cp)[blockIdx.x * 256 + t];
    l[t] = c.x + c.y + c.z + c.w;
    __syncthreads();
    for (int d = 128; d > 0; d >>= 1) {
        if (t < d) l[t] += l[t + d];
        __syncthreads();
    }
    if (t == 0) bsum[blockIdx.x] = l[0];
}

__global__ __launch_bounds__(256)
void k_scanB(const int* __restrict__ bsum, int* __restrict__ bbase,
             int* __restrict__ cv, int* __restrict__ bv)
{
    __shared__ int l[256];
    int t = threadIdx.x;
    int own = (t < 64) ? bsum[t] : 0;
    l[t] = own;
    __syncthreads();
    for (int d = 1; d < 64; d <<= 1) {
        int u = (t >= d && t < 64) ? l[t - d] : 0;
        __syncthreads();
        if (t < 64) l[t] += u;
        __syncthreads();
    }
    if (t < 64) bbase[t] = l[t] - own;
    __syncthreads();
    int4 c = ((const int4*)cv)[t];
    int s4 = c.x + c.y + c.z + c.w;
    l[t] = s4;
    __syncthreads();
    for (int d = 1; d < 256; d <<= 1) {
        int u = (t >= d) ? l[t - d] : 0;
        __syncthreads();
        l[t] += u;
        __syncthreads();
    }
    int ex = l[t] - s4;
    int4 o; o.x = ex; o.y = ex + c.x; o.z = o.y + c.y; o.w = o.z + c.z;
    ((int4*)bv)[t] = o;
    ((int4*)cv)[t] = o;
}

__global__ __launch_bounds__(256)
void k_scanC(int* __restrict__ cp, int* __restrict__ bp, const int* __restrict__ bbase)
{
    __shared__ int l[256];
    int t = threadIdx.x;
    int i = blockIdx.x * 256 + t;
    int4 c = ((const int4*)cp)[i];
    int s4 = c.x + c.y + c.z + c.w;
    l[t] = s4;
    __syncthreads();
    for (int d = 1; d < 256; d <<= 1) {
        int u = (t >= d) ? l[t - d] : 0;
        __syncthreads();
        l[t] += u;
        __syncthreads();
    }
    int ex = l[t] - s4 + bbase[blockIdx.x];
    int4 o; o.x = ex; o.y = ex + c.x; o.z = o.y + c.y; o.w = o.z + c.z;
    ((int4*)bp)[i] = o;
    ((int4*)cp)[i] = o;
}

// ---------------- scatter: entry-id lists only ----------------
__global__ __launch_bounds__(256)
void k_scatter(const int* __restrict__ vi, const int* __restrict__ pi,
               int* __restrict__ curp, int* __restrict__ curv,
               int* __restrict__ plist, int* __restrict__ vlist, int nnz)
{
    int i = blockIdx.x * blockDim.x + threadIdx.x;
    int n = gridDim.x * blockDim.x;
    for (int e = i; e < nnz; e += n) {
        int sp = atomicAdd(&curp[pi[e]], 1);
        plist[sp] = e;
        int sv = atomicAdd(&curv[vi[e]], 1);
        vlist[sv] = e;
    }
}

// ---------------- point sums: masked 8-deep gather from ebuf ----------------
__global__ __launch_bounds__(256)
void k_psum(const unsigned int* __restrict__ ebuf, const int* __restrict__ plist,
            const int* __restrict__ pbase, const int* __restrict__ pend,
            unsigned int* __restrict__ mbuf)
{
    int lane = threadIdx.x & 63, wv = threadIdx.x >> 6;
    int wave = blockIdx.x * 4 + wv, nw = gridDim.x * 4;
    for (int pt = wave; pt < NP; pt += nw) {
        int s = pbase[pt], e = pend[pt];
        float s0 = 0.f, s1 = 0.f;
        for (int b = s; b < e; b += 64) {
            int n = min(64, e - b);
            int idx = plist[b + min(lane, n - 1)];
            for (int j = 0; j < n; j += 8) {
                unsigned int u[8];
                #pragma unroll
                for (int q = 0; q < 8; ++q) {
                    int jj = (j + q < n) ? (j + q) : (n - 1);
                    int ent = __builtin_amdgcn_readlane(idx, jj);
                    u[q] = ebuf[(size_t)ent * 64 + lane];
                }
                #pragma unroll
                for (int q = 0; q < 8; ++q)
                    if (j + q < n) { s0 += bflo(u[q]); s1 += bfhi(u[q]); }
            }
        }
        float inv = 1.f / fmaxf((float)(e - s), 1.f);
        mbuf[(size_t)pt * 64 + lane] = pack2bf(s0 * inv, s1 * inv);
    }
}

// ---------------- view sums: 8 waves/block, 8 rows in flight ----------------
__global__ __launch_bounds__(512)
void k_vsum(const unsigned int* __restrict__ ebuf, const int* __restrict__ vlist,
            const int* __restrict__ vbase, const int* __restrict__ vend,
            unsigned int* __restrict__ mbuf, float* __restrict__ gs)
{
    __shared__ float2 red[8][64];
    int lane = threadIdx.x & 63, wv = threadIdx.x >> 6;
    int v = blockIdx.x;
    int s = vbase[v], e = vend[v];
    float s0 = 0.f, s1 = 0.f;
    for (int b = s + wv * 64; b < e; b += 512) {
        int n = min(64, e - b);
        int idx = vlist[b + min(lane, n - 1)];
        int j = 0;
        for (; j + 8 <= n; j += 8) {
            unsigned int u[8];
            #pragma unroll
            for (int q = 0; q < 8; ++q) {
                int r = __builtin_amdgcn_readlane(idx, j + q);
                u[q] = ebuf[(size_t)r * 64 + lane];
            }
            #pragma unroll
            for (int q = 0; q < 8; ++q) { s0 += bflo(u[q]); s1 += bfhi(u[q]); }
        }
        for (; j < n; ++j) {
            int r = __builtin_amdgcn_readlane(idx, j);
            unsigned int u = ebuf[(size_t)r * 64 + lane];
            s0 += bflo(u); s1 += bfhi(u);
        }
    }
    red[wv][lane] = make_float2(s0, s1);
    __syncthreads();
    if (wv == 0) {
        float t0 = 0.f, t1 = 0.f;
        #pragma unroll
        for (int q = 0; q < 8; ++q) { t0 += red[q][lane].x; t1 += red[q][lane].y; }
        atomicAdd(&gs[lane * 2], t0);
        atomicAdd(&gs[lane * 2 + 1], t1);
        float inv = 1.f / fmaxf((float)(e - s), 1.f);
        mbuf[(size_t)(NP + v) * 64 + lane] = pack2bf(t0 * inv, t1 * inv);
    }
}

// ---------------- MFMA tile helpers ----------------
// LDS layout: bf16 [rows][128 k], byte addr = (row*256 + k*2) ^ ((row&7)<<4)
__device__ __forceinline__ void stage_bf16(const unsigned short* __restrict__ g,
                                           unsigned short* lds, int t)
{
    #pragma unroll
    for (int i = 0; i < 8; ++i) {
        int c = i * 256 + t;
        int row = c >> 4, kb = (c & 15) * 16;
        short8 v = *(const short8*)(g + row * 128 + (c & 15) * 8);
        *(short8*)&lds[((row * 256 + kb) ^ ((row & 7) << 4)) >> 1] = v;
    }
}

__device__ __forceinline__ void mfma_tile(const unsigned short* Al, const unsigned short* Bl,
                                          int lane, int w, f32x4 acc[8][2])
{
    int lr = lane & 15, lg = lane >> 4;
    #pragma unroll
    for (int kc = 0; kc < 4; ++kc) {
        int kb = kc * 64 + lg * 16;
        int bn0 = w * 32 + lr, bn1 = bn0 + 16;
        short8 b0 = *(const short8*)&Bl[((bn0 * 256 + kb) ^ ((bn0 & 7) << 4)) >> 1];
        short8 b1 = *(const short8*)&Bl[((bn1 * 256 + kb) ^ ((bn1 & 7) << 4)) >> 1];
        #pragma unroll
        for (int m = 0; m < 8; ++m) {
            int row = m * 16 + lr;
            short8 a = *(const short8*)&Al[((row * 256 + kb) ^ ((row & 7) << 4)) >> 1];
            acc[m][0] = __builtin_amdgcn_mfma_f32_16x16x32_bf16(a, b0, acc[m][0], 0, 0, 0);
            acc[m][1] = __builtin_amdgcn_mfma_f32_16x16x32_bf16(a, b1, acc[m][1], 0, 0, 0);
        }
    }
}

// ---------------- feature GEMM -> packed (c,c+16) uint rows ----------------
__global__ __launch_bounds__(256)
void k_featgemm(const unsigned int* __restrict__ mbuf, const unsigned short* __restrict__ Wt4,
                const float* __restrict__ bSp, const float* __restrict__ bVw,
                const float* __restrict__ bGl, const float* __restrict__ gs,
                float inv_nnz, unsigned int* __restrict__ fbp)
{
    __shared__ unsigned short Al[128 * 128];
    __shared__ unsigned short Bl[128 * 128];
    int t = threadIdx.x;
    int tile = blockIdx.x;   // 0..520
    const unsigned short* Wt; const float* bias; int rowbase; int vrows = 128;
    if (tile < 512)      { Wt = Wt4;             bias = bSp; rowbase = tile * 128; }
    else if (tile < 520) { Wt = Wt4 + 16384;     bias = bVw; rowbase = NP + (tile - 512) * 128; }
    else                 { Wt = Wt4 + 2 * 16384; bias = bGl; rowbase = NP + NV; vrows = 1; }
    stage_bf16(Wt, Bl, t);
    if (tile < 520) {
        stage_bf16((const unsigned short*)(mbuf + (size_t)rowbase * 64), Al, t);
    } else {
        #pragma unroll
        for (int i = 0; i < 8; ++i) {
            int c = i * 256 + t;
            int row = c >> 4, cb = (c & 15) * 8;
            unsigned int p[4] = {0u, 0u, 0u, 0u};
            if (row == 0) {
                #pragma unroll
                for (int j = 0; j < 4; ++j)
                    p[j] = pack2bf(gs[cb + 2 * j] * inv_nnz, gs[cb + 2 * j + 1] * inv_nnz);
            }
            *(short8*)&Al[((row * 256 + cb * 2) ^ ((row & 7) << 4)) >> 1] = *(short8*)p;
        }
    }
    __syncthreads();
    f32x4 acc[8][2] = {};
    int lane = t & 63, w = t >> 6;
    mfma_tile(Al, Bl, lane, w, acc);
    int lr = lane & 15, lg = lane >> 4;
    int c0 = w * 32 + lr, c1 = c0 + 16;
    float bb0 = 0.25f * bias[c0], bb1 = 0.25f * bias[c1];
    #pragma unroll
    for (int m = 0; m < 8; ++m)
        #pragma unroll
        for (int r = 0; r < 4; ++r) {
            int row = m * 16 + lg * 4 + r;
            if (row < vrows)
                fbp[(size_t)(rowbase + row) * 64 + w * 16 + lr] =
                    pack2bf(acc[m][0][r] * 0.25f + bb0, acc[m][1][r] * 0.25f + bb1);
        }
}

// ---------------- projection: 64-row tiles, 16.5 KB LDS, high occupancy ----------------
__global__ __launch_bounds__(256)
void k_proj(const unsigned short* __restrict__ ebuf, const int* __restrict__ point_idx,
            const int* __restrict__ view_idx, const unsigned short* __restrict__ WtPr,
            const float* __restrict__ bPr, const unsigned int* __restrict__ fbp,
            float* __restrict__ out, int nnz, int ntiles)
{
    __shared__ unsigned short Al[64 * 128];    // 16 KB
    __shared__ int pI[64], vI[64];
    int t = threadIdx.x, lane = t & 63, w = t >> 6;
    int lr = lane & 15, lg = lane >> 4;
    short8 Bf[4][2];
    #pragma unroll
    for (int kc = 0; kc < 4; ++kc) {
        Bf[kc][0] = *(const short8*)(WtPr + (w * 32 + lr) * 128 + kc * 32 + lg * 8);
        Bf[kc][1] = *(const short8*)(WtPr + (w * 32 + lr + 16) * 128 + kc * 32 + lg * 8);
    }
    int c0 = w * 32 + lr, c1 = c0 + 16;
    unsigned int gw = fbp[(size_t)(NP + NV) * 64 + w * 16 + lr];
    float base0 = 0.25f * bPr[c0] + bflo(gw);
    float base1 = 0.25f * bPr[c1] + bfhi(gw);
    const unsigned int* pfp = fbp;
    const unsigned int* vfp = fbp + (size_t)NP * 64;
    for (int tile = blockIdx.x; tile < ntiles; tile += gridDim.x) {
        int e0 = tile * 64;
        int vrows = min(64, nnz - e0);
        {
            const unsigned short* g = ebuf + (size_t)e0 * 128;
            #pragma unroll
            for (int i = 0; i < 4; ++i) {
                int c = i * 256 + t;
                int row = c >> 4, kb = (c & 15) * 16;
                short8 v = ntld8h(g + row * 128 + (c & 15) * 8);
                *(short8*)&Al[((row * 256 + kb) ^ ((row & 7) << 4)) >> 1] = v;
            }
        }
        if (t < 64) pI[t] = (t < vrows) ? point_idx[e0 + t] : 0;
        else if (t < 128) { int u = t - 64; vI[u] = (u < vrows) ? view_idx[e0 + u] : 0; }
        __syncthreads();
        f32x4 acc[4][2] = {};
        #pragma unroll
        for (int kc = 0; kc < 4; ++kc) {
            int kb = kc * 64 + lg * 16;
            #pragma unroll
            for (int m = 0; m < 4; ++m) {
                int row = m * 16 + lr;
                short8 a = *(const short8*)&Al[((row * 256 + kb) ^ ((row & 7) << 4)) >> 1];
                acc[m][0] = __builtin_amdgcn_mfma_f32_16x16x32_bf16(a, Bf[kc][0], acc[m][0], 0, 0, 0);
                acc[m][1] = __builtin_amdgcn_mfma_f32_16x16x32_bf16(a, Bf[kc][1], acc[m][1], 0, 0, 0);
            }
        }
        #pragma unroll
        for (int m = 0; m < 4; ++m)
            #pragma unroll
            for (int r = 0; r < 4; ++r) {
                int row = m * 16 + lg * 4 + r;
                if (row < vrows) {
                    int p = pI[row], vv = vI[row];
                    unsigned int pu = pfp[(size_t)p * 64 + w * 16 + lr];
                    unsigned int vu = vfp[(size_t)vv * 64 + w * 16 + lr];
                    size_t o = (size_t)(e0 + row) * D;
                    ntst(&out[o + c0], acc[m][0][r] * 0.25f + base0 + bflo(pu) + bflo(vu));
                    ntst(&out[o + c1], acc[m][1][r] * 0.25f + base1 + bfhi(pu) + bfhi(vu));
                }
            }
        __syncthreads();   // protect Al/pI/vI before next tile
    }
}

extern "C" void kernel_launch(void* const* d_in, const int* in_sizes, int n_in,
                              void* d_out, int out_size, void* d_ws, size_t ws_size,
                              hipStream_t stream)
{
    const float* values    = (const float*)d_in[0];
    const int*   view_idx  = (const int*)d_in[1];
    const int*   point_idx = (const int*)d_in[2];
    const float* W_sp   = (const float*)d_in[5];
    const float* b_sp   = (const float*)d_in[6];
    const float* W_view = (const float*)d_in[7];
    const float* b_view = (const float*)d_in[8];
    const float* W_glob = (const float*)d_in[9];
    const float* b_glob = (const float*)d_in[10];
    const float* W_proj = (const float*)d_in[11];
    const float* b_proj = (const float*)d_in[12];
    int nnz = in_sizes[1];
    int ntiles128 = (nnz + 127) / 128;
    int ntiles64 = (nnz + 63) / 64;

    // ws: [gs|Cp|Cv](memset) | bsum|bbase|Bp|Bv | plist|vlist | Wt4 | mbuf | fbp | ebuf
    char* w = (char*)d_ws;
    float* gs = (float*)w;                          w += 128 * 4;
    int* Cp   = (int*)w;                            w += (size_t)NP * 4;
    int* Cv   = (int*)w;                            w += (size_t)NV * 4;
    size_t zero_bytes = (size_t)(w - (char*)d_ws);
    int* bsum = (int*)w;                            w += 64 * 4;
    int* bbase = (int*)w;                           w += 64 * 4;
    int* Bp   = (int*)w;                            w += (size_t)NP * 4;
    int* Bv   = (int*)w;                            w += (size_t)NV * 4;
    int* plist = (int*)w;                           w += (size_t)nnz * 4;
    int* vlist = (int*)w;                           w += (size_t)nnz * 4;
    unsigned short* Wt4 = (unsigned short*)w;       w += (size_t)4 * 16384 * 2;
    unsigned int* mbuf = (unsigned int*)w;          w += (size_t)(NP + NV) * 64 * 4;
    unsigned int* fbp = (unsigned int*)w;           w += (size_t)(NP + NV + 1) * 64 * 4;
    unsigned int* ebuf = (unsigned int*)w;          w += (size_t)ntiles128 * 128 * 64 * 4;

    hipMemsetAsync(d_ws, 0, zero_bytes, stream);

    hipLaunchKernelGGL(k_prep, dim3(4), dim3(256), 0, stream,
                       W_sp, W_view, W_glob, W_proj, Wt4);
    hipLaunchKernelGGL(k_cvt_count, dim3(2048), dim3(256), 0, stream,
                       values, view_idx, point_idx, Cp, Cv, (uint4*)ebuf, nnz);
    hipLaunchKernelGGL(k_scanA, dim3(64), dim3(256), 0, stream, Cp, bsum);
    hipLaunchKernelGGL(k_scanB, dim3(1), dim3(256), 0, stream, bsum, bbase, Cv, Bv);
    hipLaunchKernelGGL(k_scanC, dim3(64), dim3(256), 0, stream, Cp, Bp, bbase);
    hipLaunchKernelGGL(k_scatter, dim3(1024), dim3(256), 0, stream,
                       view_idx, point_idx, Cp, Cv, plist, vlist, nnz);
    hipLaunchKernelGGL(k_psum, dim3(2048), dim3(256), 0, stream,
                       ebuf, plist, Bp, Cp, mbuf);
    hipLaunchKernelGGL(k_vsum, dim3(NV), dim3(512), 0, stream,
                       ebuf, vlist, Bv, Cv, mbuf, gs);
    hipLaunchKernelGGL(k_featgemm, dim3(521), dim3(256), 0, stream,
                       mbuf, Wt4, b_sp, b_view, b_glob, gs, 1.f / (float)nnz, fbp);
    hipLaunchKernelGGL(k_proj, dim3(2048), dim3(256), 0, stream,
                       (const unsigned short*)ebuf, point_idx, view_idx,
                       Wt4 + (size_t)3 * 16384, b_proj, fbp,
                       (float*)d_out, nnz, ntiles64);
}

// Round 14
// 837.649 us; speedup vs baseline: 1.1606x; 1.1606x over previous
//
#include <hip/hip_runtime.h>

#define D 128
#define NP 65536
#define NV 1024
#define NCB 256   // count blocks

typedef __attribute__((ext_vector_type(8))) short short8;
typedef __attribute__((ext_vector_type(4))) float f32x4;

__device__ __forceinline__ unsigned short f2bf(float x) {
    unsigned int u = __builtin_bit_cast(unsigned int, x);
    u += 0x7FFFu + ((u >> 16) & 1u);          // round-to-nearest-even
    return (unsigned short)(u >> 16);
}
__device__ __forceinline__ unsigned int pack2bf(float a, float b) {
    return (unsigned int)f2bf(a) | ((unsigned int)f2bf(b) << 16);
}
__device__ __forceinline__ float bflo(unsigned int u) {
    return __builtin_bit_cast(float, u << 16);
}
__device__ __forceinline__ float bfhi(unsigned int u) {
    return __builtin_bit_cast(float, u & 0xFFFF0000u);
}
__device__ __forceinline__ short8 ntld8h(const unsigned short* p) {
    return __builtin_nontemporal_load((const short8*)p);
}
__device__ __forceinline__ void ntst(float* p, float v) {
    __builtin_nontemporal_store(v, p);
}

// ---------------- weight prep: W[k][n] f32 -> Wt[n][k] bf16 ----------------
__global__ __launch_bounds__(256)
void k_prep(const float* __restrict__ Wsp, const float* __restrict__ Wvw,
            const float* __restrict__ Wgl, const float* __restrict__ Wpr,
            unsigned short* __restrict__ o)
{
    const float* W = (blockIdx.x == 0) ? Wsp : (blockIdx.x == 1) ? Wvw
                   : (blockIdx.x == 2) ? Wgl : Wpr;
    unsigned short* Wt = o + (size_t)blockIdx.x * 16384;
    for (int c = threadIdx.x; c < 2048; c += 256) {
        int n = c >> 4, kb = (c & 15) * 8;
        unsigned int p[4];
        #pragma unroll
        for (int j = 0; j < 4; ++j)
            p[j] = pack2bf(W[(kb + 2 * j) * D + n], W[(kb + 2 * j + 1) * D + n]);
        *(short8*)(Wt + n * 128 + kb) = *(short8*)p;
    }
}

// ---------------- pure f32 -> bf16 entry-order copy (no atomics) ----------------
__global__ __launch_bounds__(256)
void k_cvt(const float* __restrict__ values, uint4* __restrict__ ebuf4, int nnz)
{
    size_t total = (size_t)nnz * 16;
    size_t step = (size_t)gridDim.x * 1024;
    for (size_t base = (size_t)blockIdx.x * 1024; base < total; base += step) {
        size_t i0 = base + threadIdx.x;
        f32x4 a[4], b[4];
        #pragma unroll
        for (int q = 0; q < 4; ++q) {
            size_t i = i0 + (size_t)q * 256;
            if (i < total) {
                const float* src = values + i * 8;
                a[q] = *(const f32x4*)src;
                b[q] = *(const f32x4*)(src + 4);
            }
        }
        #pragma unroll
        for (int q = 0; q < 4; ++q) {
            size_t i = i0 + (size_t)q * 256;
            if (i < total) {
                uint4 o;
                o.x = pack2bf(a[q][0], a[q][1]); o.y = pack2bf(a[q][2], a[q][3]);
                o.z = pack2bf(b[q][0], b[q][1]); o.w = pack2bf(b[q][2], b[q][3]);
                ebuf4[i] = o;
            }
        }
    }
}

// ---------------- counts: LDS-aggregated view histogram + direct point atomics ----------------
__global__ __launch_bounds__(256)
void k_count2(const int* __restrict__ vi, const int* __restrict__ pi,
              int* __restrict__ cp, int* __restrict__ vhist, int nnz)
{
    __shared__ int h[NV];
    int t = threadIdx.x;
    #pragma unroll
    for (int i = t; i < NV; i += 256) h[i] = 0;
    __syncthreads();
    int i0 = blockIdx.x * 256 + t;
    int stride = gridDim.x * 256;
    for (int e = i0; e < nnz; e += stride) {
        atomicAdd(&cp[pi[e]], 1);
        atomicAdd(&h[vi[e]], 1);
    }
    __syncthreads();
    #pragma unroll
    for (int i = t; i < NV; i += 256) vhist[blockIdx.x * NV + i] = h[i];
}

// reduce per-block view partials -> Cv (no atomics). grid 4 x 256
__global__ __launch_bounds__(256)
void k_vred(const int* __restrict__ vhist, int* __restrict__ cv)
{
    int b = blockIdx.x * 256 + threadIdx.x;   // bin
    int s = 0;
    for (int p = 0; p < NCB; ++p) s += vhist[p * NV + b];
    cv[b] = s;
}

// ---------------- scans ----------------
__global__ __launch_bounds__(256)
void k_scanA(const int* __restrict__ cp, int* __restrict__ bsum)
{
    __shared__ int l[256];
    int t = threadIdx.x;
    int4 c = ((const int4*)cp)[blockIdx.x * 256 + t];
    l[t] = c.x + c.y + c.z + c.w;
    __syncthreads();
    for (int d = 128; d > 0; d >>= 1) {
        if (t < d) l[t] += l[t + d];
        __syncthreads();
    }
    if (t == 0) bsum[blockIdx.x] = l[0];
}

__global__ __launch_bounds__(256)
void k_scanB(const int* __restrict__ bsum, int* __restrict__ bbase,
             int* __restrict__ cv, int* __restrict__ bv)
{
    __shared__ int l[256];
    int t = threadIdx.x;
    int own = (t < 64) ? bsum[t] : 0;
    l[t] = own;
    __syncthreads();
    for (int d = 1; d < 64; d <<= 1) {
        int u = (t >= d && t < 64) ? l[t - d] : 0;
        __syncthreads();
        if (t < 64) l[t] += u;
        __syncthreads();
    }
    if (t < 64) bbase[t] = l[t] - own;
    __syncthreads();
    int4 c = ((const int4*)cv)[t];
    int s4 = c.x + c.y + c.z + c.w;
    l[t] = s4;
    __syncthreads();
    for (int d = 1; d < 256; d <<= 1) {
        int u = (t >= d) ? l[t - d] : 0;
        __syncthreads();
        l[t] += u;
        __syncthreads();
    }
    int ex = l[t] - s4;
    int4 o; o.x = ex; o.y = ex + c.x; o.z = o.y + c.y; o.w = o.z + c.z;
    ((int4*)bv)[t] = o;
    ((int4*)cv)[t] = o;
}

__global__ __launch_bounds__(256)
void k_scanC(int* __restrict__ cp, int* __restrict__ bp, const int* __restrict__ bbase)
{
    __shared__ int l[256];
    int t = threadIdx.x;
    int i = blockIdx.x * 256 + t;
    int4 c = ((const int4*)cp)[i];
    int s4 = c.x + c.y + c.z + c.w;
    l[t] = s4;
    __syncthreads();
    for (int d = 1; d < 256; d <<= 1) {
        int u = (t >= d) ? l[t - d] : 0;
        __syncthreads();
        l[t] += u;
        __syncthreads();
    }
    int ex = l[t] - s4 + bbase[blockIdx.x];
    int4 o; o.x = ex; o.y = ex + c.x; o.z = o.y + c.y; o.w = o.z + c.z;
    ((int4*)bp)[i] = o;
    ((int4*)cp)[i] = o;
}

// ---------------- scatter: entry-id lists only ----------------
__global__ __launch_bounds__(256)
void k_scatter(const int* __restrict__ vi, const int* __restrict__ pi,
               int* __restrict__ curp, int* __restrict__ curv,
               int* __restrict__ plist, int* __restrict__ vlist, int nnz)
{
    int i = blockIdx.x * blockDim.x + threadIdx.x;
    int n = gridDim.x * blockDim.x;
    for (int e = i; e < nnz; e += n) {
        int sp = atomicAdd(&curp[pi[e]], 1);
        plist[sp] = e;
        int sv = atomicAdd(&curv[vi[e]], 1);
        vlist[sv] = e;
    }
}

// ---------------- point sums: masked 8-deep gather from ebuf ----------------
__global__ __launch_bounds__(256)
void k_psum(const unsigned int* __restrict__ ebuf, const int* __restrict__ plist,
            const int* __restrict__ pbase, const int* __restrict__ pend,
            unsigned int* __restrict__ mbuf)
{
    int lane = threadIdx.x & 63, wv = threadIdx.x >> 6;
    int wave = blockIdx.x * 4 + wv, nw = gridDim.x * 4;
    for (int pt = wave; pt < NP; pt += nw) {
        int s = pbase[pt], e = pend[pt];
        float s0 = 0.f, s1 = 0.f;
        for (int b = s; b < e; b += 64) {
            int n = min(64, e - b);
            int idx = plist[b + min(lane, n - 1)];
            for (int j = 0; j < n; j += 8) {
                unsigned int u[8];
                #pragma unroll
                for (int q = 0; q < 8; ++q) {
                    int jj = (j + q < n) ? (j + q) : (n - 1);
                    int ent = __builtin_amdgcn_readlane(idx, jj);
                    u[q] = ebuf[(size_t)ent * 64 + lane];
                }
                #pragma unroll
                for (int q = 0; q < 8; ++q)
                    if (j + q < n) { s0 += bflo(u[q]); s1 += bfhi(u[q]); }
            }
        }
        float inv = 1.f / fmaxf((float)(e - s), 1.f);
        mbuf[(size_t)pt * 64 + lane] = pack2bf(s0 * inv, s1 * inv);
    }
}

// ---------------- view sums: 8 waves/block, 8 rows in flight ----------------
__global__ __launch_bounds__(512)
void k_vsum(const unsigned int* __restrict__ ebuf, const int* __restrict__ vlist,
            const int* __restrict__ vbase, const int* __restrict__ vend,
            unsigned int* __restrict__ mbuf, float* __restrict__ gs)
{
    __shared__ float2 red[8][64];
    int lane = threadIdx.x & 63, wv = threadIdx.x >> 6;
    int v = blockIdx.x;
    int s = vbase[v], e = vend[v];
    float s0 = 0.f, s1 = 0.f;
    for (int b = s + wv * 64; b < e; b += 512) {
        int n = min(64, e - b);
        int idx = vlist[b + min(lane, n - 1)];
        int j = 0;
        for (; j + 8 <= n; j += 8) {
            unsigned int u[8];
            #pragma unroll
            for (int q = 0; q < 8; ++q) {
                int r = __builtin_amdgcn_readlane(idx, j + q);
                u[q] = ebuf[(size_t)r * 64 + lane];
            }
            #pragma unroll
            for (int q = 0; q < 8; ++q) { s0 += bflo(u[q]); s1 += bfhi(u[q]); }
        }
        for (; j < n; ++j) {
            int r = __builtin_amdgcn_readlane(idx, j);
            unsigned int u = ebuf[(size_t)r * 64 + lane];
            s0 += bflo(u); s1 += bfhi(u);
        }
    }
    red[wv][lane] = make_float2(s0, s1);
    __syncthreads();
    if (wv == 0) {
        float t0 = 0.f, t1 = 0.f;
        #pragma unroll
        for (int q = 0; q < 8; ++q) { t0 += red[q][lane].x; t1 += red[q][lane].y; }
        atomicAdd(&gs[lane * 2], t0);
        atomicAdd(&gs[lane * 2 + 1], t1);
        float inv = 1.f / fmaxf((float)(e - s), 1.f);
        mbuf[(size_t)(NP + v) * 64 + lane] = pack2bf(t0 * inv, t1 * inv);
    }
}

// ---------------- MFMA tile helpers ----------------
// LDS layout: bf16 [rows][128 k], byte addr = (row*256 + k*2) ^ ((row&7)<<4)
__device__ __forceinline__ void stage_bf16(const unsigned short* __restrict__ g,
                                           unsigned short* lds, int t)
{
    #pragma unroll
    for (int i = 0; i < 8; ++i) {
        int c = i * 256 + t;
        int row = c >> 4, kb = (c & 15) * 16;
        short8 v = *(const short8*)(g + row * 128 + (c & 15) * 8);
        *(short8*)&lds[((row * 256 + kb) ^ ((row & 7) << 4)) >> 1] = v;
    }
}

__device__ __forceinline__ void mfma_tile(const unsigned short* Al, const unsigned short* Bl,
                                          int lane, int w, f32x4 acc[8][2])
{
    int lr = lane & 15, lg = lane >> 4;
    #pragma unroll
    for (int kc = 0; kc < 4; ++kc) {
        int kb = kc * 64 + lg * 16;
        int bn0 = w * 32 + lr, bn1 = bn0 + 16;
        short8 b0 = *(const short8*)&Bl[((bn0 * 256 + kb) ^ ((bn0 & 7) << 4)) >> 1];
        short8 b1 = *(const short8*)&Bl[((bn1 * 256 + kb) ^ ((bn1 & 7) << 4)) >> 1];
        #pragma unroll
        for (int m = 0; m < 8; ++m) {
            int row = m * 16 + lr;
            short8 a = *(const short8*)&Al[((row * 256 + kb) ^ ((row & 7) << 4)) >> 1];
            acc[m][0] = __builtin_amdgcn_mfma_f32_16x16x32_bf16(a, b0, acc[m][0], 0, 0, 0);
            acc[m][1] = __builtin_amdgcn_mfma_f32_16x16x32_bf16(a, b1, acc[m][1], 0, 0, 0);
        }
    }
}

// ---------------- feature GEMM -> packed (c,c+16) uint rows ----------------
__global__ __launch_bounds__(256)
void k_featgemm(const unsigned int* __restrict__ mbuf, const unsigned short* __restrict__ Wt4,
                const float* __restrict__ bSp, const float* __restrict__ bVw,
                const float* __restrict__ bGl, const float* __restrict__ gs,
                float inv_nnz, unsigned int* __restrict__ fbp)
{
    __shared__ unsigned short Al[128 * 128];
    __shared__ unsigned short Bl[128 * 128];
    int t = threadIdx.x;
    int tile = blockIdx.x;   // 0..520
    const unsigned short* Wt; const float* bias; int rowbase; int vrows = 128;
    if (tile < 512)      { Wt = Wt4;             bias = bSp; rowbase = tile * 128; }
    else if (tile < 520) { Wt = Wt4 + 16384;     bias = bVw; rowbase = NP + (tile - 512) * 128; }
    else                 { Wt = Wt4 + 2 * 16384; bias = bGl; rowbase = NP + NV; vrows = 1; }
    stage_bf16(Wt, Bl, t);
    if (tile < 520) {
        stage_bf16((const unsigned short*)(mbuf + (size_t)rowbase * 64), Al, t);
    } else {
        #pragma unroll
        for (int i = 0; i < 8; ++i) {
            int c = i * 256 + t;
            int row = c >> 4, cb = (c & 15) * 8;
            unsigned int p[4] = {0u, 0u, 0u, 0u};
            if (row == 0) {
                #pragma unroll
                for (int j = 0; j < 4; ++j)
                    p[j] = pack2bf(gs[cb + 2 * j] * inv_nnz, gs[cb + 2 * j + 1] * inv_nnz);
            }
            *(short8*)&Al[((row * 256 + cb * 2) ^ ((row & 7) << 4)) >> 1] = *(short8*)p;
        }
    }
    __syncthreads();
    f32x4 acc[8][2] = {};
    int lane = t & 63, w = t >> 6;
    mfma_tile(Al, Bl, lane, w, acc);
    int lr = lane & 15, lg = lane >> 4;
    int c0 = w * 32 + lr, c1 = c0 + 16;
    float bb0 = 0.25f * bias[c0], bb1 = 0.25f * bias[c1];
    #pragma unroll
    for (int m = 0; m < 8; ++m)
        #pragma unroll
        for (int r = 0; r < 4; ++r) {
            int row = m * 16 + lg * 4 + r;
            if (row < vrows)
                fbp[(size_t)(rowbase + row) * 64 + w * 16 + lr] =
                    pack2bf(acc[m][0][r] * 0.25f + bb0, acc[m][1][r] * 0.25f + bb1);
        }
}

// ---------------- projection: 64-row tiles, 16.5 KB LDS, high occupancy ----------------
__global__ __launch_bounds__(256)
void k_proj(const unsigned short* __restrict__ ebuf, const int* __restrict__ point_idx,
            const int* __restrict__ view_idx, const unsigned short* __restrict__ WtPr,
            const float* __restrict__ bPr, const unsigned int* __restrict__ fbp,
            float* __restrict__ out, int nnz, int ntiles)
{
    __shared__ unsigned short Al[64 * 128];    // 16 KB
    __shared__ int pI[64], vI[64];
    int t = threadIdx.x, lane = t & 63, w = t >> 6;
    int lr = lane & 15, lg = lane >> 4;
    short8 Bf[4][2];
    #pragma unroll
    for (int kc = 0; kc < 4; ++kc) {
        Bf[kc][0] = *(const short8*)(WtPr + (w * 32 + lr) * 128 + kc * 32 + lg * 8);
        Bf[kc][1] = *(const short8*)(WtPr + (w * 32 + lr + 16) * 128 + kc * 32 + lg * 8);
    }
    int c0 = w * 32 + lr, c1 = c0 + 16;
    unsigned int gw = fbp[(size_t)(NP + NV) * 64 + w * 16 + lr];
    float base0 = 0.25f * bPr[c0] + bflo(gw);
    float base1 = 0.25f * bPr[c1] + bfhi(gw);
    const unsigned int* pfp = fbp;
    const unsigned int* vfp = fbp + (size_t)NP * 64;
    for (int tile = blockIdx.x; tile < ntiles; tile += gridDim.x) {
        int e0 = tile * 64;
        int vrows = min(64, nnz - e0);
        {
            const unsigned short* g = ebuf + (size_t)e0 * 128;
            #pragma unroll
            for (int i = 0; i < 4; ++i) {
                int c = i * 256 + t;
                int row = c >> 4, kb = (c & 15) * 16;
                short8 v = ntld8h(g + row * 128 + (c & 15) * 8);
                *(short8*)&Al[((row * 256 + kb) ^ ((row & 7) << 4)) >> 1] = v;
            }
        }
        if (t < 64) pI[t] = (t < vrows) ? point_idx[e0 + t] : 0;
        else if (t < 128) { int u = t - 64; vI[u] = (u < vrows) ? view_idx[e0 + u] : 0; }
        __syncthreads();
        f32x4 acc[4][2] = {};
        #pragma unroll
        for (int kc = 0; kc < 4; ++kc) {
            int kb = kc * 64 + lg * 16;
            #pragma unroll
            for (int m = 0; m < 4; ++m) {
                int row = m * 16 + lr;
                short8 a = *(const short8*)&Al[((row * 256 + kb) ^ ((row & 7) << 4)) >> 1];
                acc[m][0] = __builtin_amdgcn_mfma_f32_16x16x32_bf16(a, Bf[kc][0], acc[m][0], 0, 0, 0);
                acc[m][1] = __builtin_amdgcn_mfma_f32_16x16x32_bf16(a, Bf[kc][1], acc[m][1], 0, 0, 0);
            }
        }
        #pragma unroll
        for (int m = 0; m < 4; ++m)
            #pragma unroll
            for (int r = 0; r < 4; ++r) {
                int row = m * 16 + lg * 4 + r;
                if (row < vrows) {
                    int p = pI[row], vv = vI[row];
                    unsigned int pu = pfp[(size_t)p * 64 + w * 16 + lr];
                    unsigned int vu = vfp[(size_t)vv * 64 + w * 16 + lr];
                    size_t o = (size_t)(e0 + row) * D;
                    ntst(&out[o + c0], acc[m][0][r] * 0.25f + base0 + bflo(pu) + bflo(vu));
                    ntst(&out[o + c1], acc[m][1][r] * 0.25f + base1 + bfhi(pu) + bfhi(vu));
                }
            }
        __syncthreads();   // protect Al/pI/vI before next tile
    }
}

extern "C" void kernel_launch(void* const* d_in, const int* in_sizes, int n_in,
                              void* d_out, int out_size, void* d_ws, size_t ws_size,
                              hipStream_t stream)
{
    const float* values    = (const float*)d_in[0];
    const int*   view_idx  = (const int*)d_in[1];
    const int*   point_idx = (const int*)d_in[2];
    const float* W_sp   = (const float*)d_in[5];
    const float* b_sp   = (const float*)d_in[6];
    const float* W_view = (const float*)d_in[7];
    const float* b_view = (const float*)d_in[8];
    const float* W_glob = (const float*)d_in[9];
    const float* b_glob = (const float*)d_in[10];
    const float* W_proj = (const float*)d_in[11];
    const float* b_proj = (const float*)d_in[12];
    int nnz = in_sizes[1];
    int ntiles128 = (nnz + 127) / 128;
    int ntiles64 = (nnz + 63) / 64;

    // ws: [gs|Cp|Cv](memset) | bsum|bbase|Bp|Bv | vhist | plist|vlist | Wt4 | mbuf | fbp | ebuf
    char* w = (char*)d_ws;
    float* gs = (float*)w;                          w += 128 * 4;
    int* Cp   = (int*)w;                            w += (size_t)NP * 4;
    int* Cv   = (int*)w;                            w += (size_t)NV * 4;
    size_t zero_bytes = (size_t)(w - (char*)d_ws);
    int* bsum = (int*)w;                            w += 64 * 4;
    int* bbase = (int*)w;                           w += 64 * 4;
    int* Bp   = (int*)w;                            w += (size_t)NP * 4;
    int* Bv   = (int*)w;                            w += (size_t)NV * 4;
    int* vhist = (int*)w;                           w += (size_t)NCB * NV * 4;
    int* plist = (int*)w;                           w += (size_t)nnz * 4;
    int* vlist = (int*)w;                           w += (size_t)nnz * 4;
    unsigned short* Wt4 = (unsigned short*)w;       w += (size_t)4 * 16384 * 2;
    unsigned int* mbuf = (unsigned int*)w;          w += (size_t)(NP + NV) * 64 * 4;
    unsigned int* fbp = (unsigned int*)w;           w += (size_t)(NP + NV + 1) * 64 * 4;
    unsigned int* ebuf = (unsigned int*)w;          w += (size_t)ntiles128 * 128 * 64 * 4;

    hipMemsetAsync(d_ws, 0, zero_bytes, stream);

    hipLaunchKernelGGL(k_prep, dim3(4), dim3(256), 0, stream,
                       W_sp, W_view, W_glob, W_proj, Wt4);
    hipLaunchKernelGGL(k_cvt, dim3(2048), dim3(256), 0, stream,
                       values, (uint4*)ebuf, nnz);
    hipLaunchKernelGGL(k_count2, dim3(NCB), dim3(256), 0, stream,
                       view_idx, point_idx, Cp, vhist, nnz);
    hipLaunchKernelGGL(k_vred, dim3(NV / 256), dim3(256), 0, stream, vhist, Cv);
    hipLaunchKernelGGL(k_scanA, dim3(64), dim3(256), 0, stream, Cp, bsum);
    hipLaunchKernelGGL(k_scanB, dim3(1), dim3(256), 0, stream, bsum, bbase, Cv, Bv);
    hipLaunchKernelGGL(k_scanC, dim3(64), dim3(256), 0, stream, Cp, Bp, bbase);
    hipLaunchKernelGGL(k_scatter, dim3(1024), dim3(256), 0, stream,
                       view_idx, point_idx, Cp, Cv, plist, vlist, nnz);
    hipLaunchKernelGGL(k_psum, dim3(2048), dim3(256), 0, stream,
                       ebuf, plist, Bp, Cp, mbuf);
    hipLaunchKernelGGL(k_vsum, dim3(NV), dim3(512), 0, stream,
                       ebuf, vlist, Bv, Cv, mbuf, gs);
    hipLaunchKernelGGL(k_featgemm, dim3(521), dim3(256), 0, stream,
                       mbuf, Wt4, b_sp, b_view, b_glob, gs, 1.f / (float)nnz, fbp);
    hipLaunchKernelGGL(k_proj, dim3(2048), dim3(256), 0, stream,
                       (const unsigned short*)ebuf, point_idx, view_idx,
                       Wt4 + (size_t)3 * 16384, b_proj, fbp,
                       (float*)d_out, nnz, ntiles64);
}

// Round 15
// 650.501 us; speedup vs baseline: 1.4945x; 1.2877x over previous
//
#include <hip/hip_runtime.h>

#define D 128
#define NP 65536
#define NV 1024
#define NCB 256   // count blocks
#define NSB 256   // scatter blocks

typedef __attribute__((ext_vector_type(8))) short short8;
typedef __attribute__((ext_vector_type(4))) float f32x4;

__device__ __forceinline__ unsigned short f2bf(float x) {
    unsigned int u = __builtin_bit_cast(unsigned int, x);
    u += 0x7FFFu + ((u >> 16) & 1u);          // round-to-nearest-even
    return (unsigned short)(u >> 16);
}
__device__ __forceinline__ unsigned int pack2bf(float a, float b) {
    return (unsigned int)f2bf(a) | ((unsigned int)f2bf(b) << 16);
}
__device__ __forceinline__ float bflo(unsigned int u) {
    return __builtin_bit_cast(float, u << 16);
}
__device__ __forceinline__ float bfhi(unsigned int u) {
    return __builtin_bit_cast(float, u & 0xFFFF0000u);
}
__device__ __forceinline__ short8 ntld8h(const unsigned short* p) {
    return __builtin_nontemporal_load((const short8*)p);
}
__device__ __forceinline__ void ntst(float* p, float v) {
    __builtin_nontemporal_store(v, p);
}

// ---------------- weight prep: W[k][n] f32 -> Wt[n][k] bf16 ----------------
__global__ __launch_bounds__(256)
void k_prep(const float* __restrict__ Wsp, const float* __restrict__ Wvw,
            const float* __restrict__ Wgl, const float* __restrict__ Wpr,
            unsigned short* __restrict__ o)
{
    const float* W = (blockIdx.x == 0) ? Wsp : (blockIdx.x == 1) ? Wvw
                   : (blockIdx.x == 2) ? Wgl : Wpr;
    unsigned short* Wt = o + (size_t)blockIdx.x * 16384;
    for (int c = threadIdx.x; c < 2048; c += 256) {
        int n = c >> 4, kb = (c & 15) * 8;
        unsigned int p[4];
        #pragma unroll
        for (int j = 0; j < 4; ++j)
            p[j] = pack2bf(W[(kb + 2 * j) * D + n], W[(kb + 2 * j + 1) * D + n]);
        *(short8*)(Wt + n * 128 + kb) = *(short8*)p;
    }
}

// ---------------- pure f32 -> bf16 entry-order copy (no atomics) ----------------
__global__ __launch_bounds__(256)
void k_cvt(const float* __restrict__ values, uint4* __restrict__ ebuf4, int nnz)
{
    size_t total = (size_t)nnz * 16;
    size_t step = (size_t)gridDim.x * 1024;
    for (size_t base = (size_t)blockIdx.x * 1024; base < total; base += step) {
        size_t i0 = base + threadIdx.x;
        f32x4 a[4], b[4];
        #pragma unroll
        for (int q = 0; q < 4; ++q) {
            size_t i = i0 + (size_t)q * 256;
            if (i < total) {
                const float* src = values + i * 8;
                a[q] = *(const f32x4*)src;
                b[q] = *(const f32x4*)(src + 4);
            }
        }
        #pragma unroll
        for (int q = 0; q < 4; ++q) {
            size_t i = i0 + (size_t)q * 256;
            if (i < total) {
                uint4 o;
                o.x = pack2bf(a[q][0], a[q][1]); o.y = pack2bf(a[q][2], a[q][3]);
                o.z = pack2bf(b[q][0], b[q][1]); o.w = pack2bf(b[q][2], b[q][3]);
                ebuf4[i] = o;
            }
        }
    }
}

// ---------------- counts: LDS-aggregated view histogram + direct point atomics ----------------
__global__ __launch_bounds__(256)
void k_count2(const int* __restrict__ vi, const int* __restrict__ pi,
              int* __restrict__ cp, int* __restrict__ vhist, int nnz)
{
    __shared__ int h[NV];
    int t = threadIdx.x;
    #pragma unroll
    for (int i = t; i < NV; i += 256) h[i] = 0;
    __syncthreads();
    int i0 = blockIdx.x * 256 + t;
    int stride = gridDim.x * 256;
    for (int e = i0; e < nnz; e += stride) {
        atomicAdd(&cp[pi[e]], 1);
        atomicAdd(&h[vi[e]], 1);
    }
    __syncthreads();
    #pragma unroll
    for (int i = t; i < NV; i += 256) vhist[blockIdx.x * NV + i] = h[i];
}

// reduce per-block view partials -> Cv (no atomics). grid 4 x 256
__global__ __launch_bounds__(256)
void k_vred(const int* __restrict__ vhist, int* __restrict__ cv)
{
    int b = blockIdx.x * 256 + threadIdx.x;   // bin
    int s = 0;
    for (int p = 0; p < NCB; ++p) s += vhist[p * NV + b];
    cv[b] = s;
}

// ---------------- scans ----------------
__global__ __launch_bounds__(256)
void k_scanA(const int* __restrict__ cp, int* __restrict__ bsum)
{
    __shared__ int l[256];
    int t = threadIdx.x;
    int4 c = ((const int4*)cp)[blockIdx.x * 256 + t];
    l[t] = c.x + c.y + c.z + c.w;
    __syncthreads();
    for (int d = 128; d > 0; d >>= 1) {
        if (t < d) l[t] += l[t + d];
        __syncthreads();
    }
    if (t == 0) bsum[blockIdx.x] = l[0];
}

__global__ __launch_bounds__(256)
void k_scanB(const int* __restrict__ bsum, int* __restrict__ bbase,
             int* __restrict__ cv, int* __restrict__ bv)
{
    __shared__ int l[256];
    int t = threadIdx.x;
    int own = (t < 64) ? bsum[t] : 0;
    l[t] = own;
    __syncthreads();
    for (int d = 1; d < 64; d <<= 1) {
        int u = (t >= d && t < 64) ? l[t - d] : 0;
        __syncthreads();
        if (t < 64) l[t] += u;
        __syncthreads();
    }
    if (t < 64) bbase[t] = l[t] - own;
    __syncthreads();
    int4 c = ((const int4*)cv)[t];
    int s4 = c.x + c.y + c.z + c.w;
    l[t] = s4;
    __syncthreads();
    for (int d = 1; d < 256; d <<= 1) {
        int u = (t >= d) ? l[t - d] : 0;
        __syncthreads();
        l[t] += u;
        __syncthreads();
    }
    int ex = l[t] - s4;
    int4 o; o.x = ex; o.y = ex + c.x; o.z = o.y + c.y; o.w = o.z + c.z;
    ((int4*)bv)[t] = o;
    ((int4*)cv)[t] = o;
}

__global__ __launch_bounds__(256)
void k_scanC(int* __restrict__ cp, int* __restrict__ bp, const int* __restrict__ bbase)
{
    __shared__ int l[256];
    int t = threadIdx.x;
    int i = blockIdx.x * 256 + t;
    int4 c = ((const int4*)cp)[i];
    int s4 = c.x + c.y + c.z + c.w;
    l[t] = s4;
    __syncthreads();
    for (int d = 1; d < 256; d <<= 1) {
        int u = (t >= d) ? l[t - d] : 0;
        __syncthreads();
        l[t] += u;
        __syncthreads();
    }
    int ex = l[t] - s4 + bbase[blockIdx.x];
    int4 o; o.x = ex; o.y = ex + c.x; o.z = o.y + c.y; o.w = o.z + c.z;
    ((int4*)bp)[i] = o;
    ((int4*)cp)[i] = o;
}

// ---------------- scatter: two-level binned views, direct points ----------------
__global__ __launch_bounds__(256)
void k_scatter(const int* __restrict__ vi, const int* __restrict__ pi,
               int* __restrict__ curp, int* __restrict__ curv,
               int* __restrict__ plist, int* __restrict__ vlist, int nnz)
{
    __shared__ int h[NV];
    __shared__ int hbase[NV];
    int t = threadIdx.x;
    #pragma unroll
    for (int i = t; i < NV; i += 256) h[i] = 0;
    __syncthreads();
    int chunk = (nnz + gridDim.x - 1) / gridDim.x;   // <= 4096 for 256 blocks
    int s = blockIdx.x * chunk;
    int e = min(nnz, s + chunk);
    int v_[16], lr_[16];
    #pragma unroll
    for (int k = 0; k < 16; ++k) {
        int idx = s + k * 256 + t;
        v_[k] = -1; lr_[k] = 0;
        if (idx < e) {
            int v = vi[idx];
            v_[k] = v;
            lr_[k] = atomicAdd(&h[v], 1);
            int sp = atomicAdd(&curp[pi[idx]], 1);
            plist[sp] = idx;
        }
    }
    __syncthreads();
    #pragma unroll
    for (int i = t; i < NV; i += 256) {
        int c = h[i];
        hbase[i] = c ? atomicAdd(&curv[i], c) : 0;
    }
    __syncthreads();
    #pragma unroll
    for (int k = 0; k < 16; ++k) {
        int idx = s + k * 256 + t;
        if (idx < e) vlist[hbase[v_[k]] + lr_[k]] = idx;
    }
}

// ---------------- point sums: masked 16-deep gather from ebuf ----------------
__global__ __launch_bounds__(256)
void k_psum(const unsigned int* __restrict__ ebuf, const int* __restrict__ plist,
            const int* __restrict__ pbase, const int* __restrict__ pend,
            unsigned int* __restrict__ mbuf)
{
    int lane = threadIdx.x & 63, wv = threadIdx.x >> 6;
    int wave = blockIdx.x * 4 + wv, nw = gridDim.x * 4;
    for (int pt = wave; pt < NP; pt += nw) {
        int s = pbase[pt], e = pend[pt];
        float s0 = 0.f, s1 = 0.f;
        for (int b = s; b < e; b += 64) {
            int n = min(64, e - b);
            int idx = plist[b + min(lane, n - 1)];
            for (int j = 0; j < n; j += 16) {
                unsigned int u[16];
                #pragma unroll
                for (int q = 0; q < 16; ++q) {
                    int jj = (j + q < n) ? (j + q) : (n - 1);
                    int ent = __builtin_amdgcn_readlane(idx, jj);
                    u[q] = ebuf[(size_t)ent * 64 + lane];
                }
                #pragma unroll
                for (int q = 0; q < 16; ++q)
                    if (j + q < n) { s0 += bflo(u[q]); s1 += bfhi(u[q]); }
            }
        }
        float inv = 1.f / fmaxf((float)(e - s), 1.f);
        mbuf[(size_t)pt * 64 + lane] = pack2bf(s0 * inv, s1 * inv);
    }
}

// ---------------- view sums: 8 waves/block, 16 rows in flight ----------------
__global__ __launch_bounds__(512)
void k_vsum(const unsigned int* __restrict__ ebuf, const int* __restrict__ vlist,
            const int* __restrict__ vbase, const int* __restrict__ vend,
            unsigned int* __restrict__ mbuf, float* __restrict__ gs)
{
    __shared__ float2 red[8][64];
    int lane = threadIdx.x & 63, wv = threadIdx.x >> 6;
    int v = blockIdx.x;
    int s = vbase[v], e = vend[v];
    float s0 = 0.f, s1 = 0.f;
    for (int b = s + wv * 64; b < e; b += 512) {
        int n = min(64, e - b);
        int idx = vlist[b + min(lane, n - 1)];
        for (int j = 0; j < n; j += 16) {
            unsigned int u[16];
            #pragma unroll
            for (int q = 0; q < 16; ++q) {
                int jj = (j + q < n) ? (j + q) : (n - 1);
                int r = __builtin_amdgcn_readlane(idx, jj);
                u[q] = ebuf[(size_t)r * 64 + lane];
            }
            #pragma unroll
            for (int q = 0; q < 16; ++q)
                if (j + q < n) { s0 += bflo(u[q]); s1 += bfhi(u[q]); }
        }
    }
    red[wv][lane] = make_float2(s0, s1);
    __syncthreads();
    if (wv == 0) {
        float t0 = 0.f, t1 = 0.f;
        #pragma unroll
        for (int q = 0; q < 8; ++q) { t0 += red[q][lane].x; t1 += red[q][lane].y; }
        atomicAdd(&gs[lane * 2], t0);
        atomicAdd(&gs[lane * 2 + 1], t1);
        float inv = 1.f / fmaxf((float)(e - s), 1.f);
        mbuf[(size_t)(NP + v) * 64 + lane] = pack2bf(t0 * inv, t1 * inv);
    }
}

// ---------------- MFMA tile helpers ----------------
// LDS layout: bf16 [rows][128 k], byte addr = (row*256 + k*2) ^ ((row&7)<<4)
__device__ __forceinline__ void stage_bf16(const unsigned short* __restrict__ g,
                                           unsigned short* lds, int t)
{
    #pragma unroll
    for (int i = 0; i < 8; ++i) {
        int c = i * 256 + t;
        int row = c >> 4, kb = (c & 15) * 16;
        short8 v = *(const short8*)(g + row * 128 + (c & 15) * 8);
        *(short8*)&lds[((row * 256 + kb) ^ ((row & 7) << 4)) >> 1] = v;
    }
}

__device__ __forceinline__ void mfma_tile(const unsigned short* Al, const unsigned short* Bl,
                                          int lane, int w, f32x4 acc[8][2])
{
    int lr = lane & 15, lg = lane >> 4;
    #pragma unroll
    for (int kc = 0; kc < 4; ++kc) {
        int kb = kc * 64 + lg * 16;
        int bn0 = w * 32 + lr, bn1 = bn0 + 16;
        short8 b0 = *(const short8*)&Bl[((bn0 * 256 + kb) ^ ((bn0 & 7) << 4)) >> 1];
        short8 b1 = *(const short8*)&Bl[((bn1 * 256 + kb) ^ ((bn1 & 7) << 4)) >> 1];
        #pragma unroll
        for (int m = 0; m < 8; ++m) {
            int row = m * 16 + lr;
            short8 a = *(const short8*)&Al[((row * 256 + kb) ^ ((row & 7) << 4)) >> 1];
            acc[m][0] = __builtin_amdgcn_mfma_f32_16x16x32_bf16(a, b0, acc[m][0], 0, 0, 0);
            acc[m][1] = __builtin_amdgcn_mfma_f32_16x16x32_bf16(a, b1, acc[m][1], 0, 0, 0);
        }
    }
}

// ---------------- feature GEMM -> packed (c,c+16) uint rows ----------------
__global__ __launch_bounds__(256)
void k_featgemm(const unsigned int* __restrict__ mbuf, const unsigned short* __restrict__ Wt4,
                const float* __restrict__ bSp, const float* __restrict__ bVw,
                const float* __restrict__ bGl, const float* __restrict__ gs,
                float inv_nnz, unsigned int* __restrict__ fbp)
{
    __shared__ unsigned short Al[128 * 128];
    __shared__ unsigned short Bl[128 * 128];
    int t = threadIdx.x;
    int tile = blockIdx.x;   // 0..520
    const unsigned short* Wt; const float* bias; int rowbase; int vrows = 128;
    if (tile < 512)      { Wt = Wt4;             bias = bSp; rowbase = tile * 128; }
    else if (tile < 520) { Wt = Wt4 + 16384;     bias = bVw; rowbase = NP + (tile - 512) * 128; }
    else                 { Wt = Wt4 + 2 * 16384; bias = bGl; rowbase = NP + NV; vrows = 1; }
    stage_bf16(Wt, Bl, t);
    if (tile < 520) {
        stage_bf16((const unsigned short*)(mbuf + (size_t)rowbase * 64), Al, t);
    } else {
        #pragma unroll
        for (int i = 0; i < 8; ++i) {
            int c = i * 256 + t;
            int row = c >> 4, cb = (c & 15) * 8;
            unsigned int p[4] = {0u, 0u, 0u, 0u};
            if (row == 0) {
                #pragma unroll
                for (int j = 0; j < 4; ++j)
                    p[j] = pack2bf(gs[cb + 2 * j] * inv_nnz, gs[cb + 2 * j + 1] * inv_nnz);
            }
            *(short8*)&Al[((row * 256 + cb * 2) ^ ((row & 7) << 4)) >> 1] = *(short8*)p;
        }
    }
    __syncthreads();
    f32x4 acc[8][2] = {};
    int lane = t & 63, w = t >> 6;
    mfma_tile(Al, Bl, lane, w, acc);
    int lr = lane & 15, lg = lane >> 4;
    int c0 = w * 32 + lr, c1 = c0 + 16;
    float bb0 = 0.25f * bias[c0], bb1 = 0.25f * bias[c1];
    #pragma unroll
    for (int m = 0; m < 8; ++m)
        #pragma unroll
        for (int r = 0; r < 4; ++r) {
            int row = m * 16 + lg * 4 + r;
            if (row < vrows)
                fbp[(size_t)(rowbase + row) * 64 + w * 16 + lr] =
                    pack2bf(acc[m][0][r] * 0.25f + bb0, acc[m][1][r] * 0.25f + bb1);
        }
}

// ---------------- projection: 64-row tiles, 16.5 KB LDS, high occupancy ----------------
__global__ __launch_bounds__(256)
void k_proj(const unsigned short* __restrict__ ebuf, const int* __restrict__ point_idx,
            const int* __restrict__ view_idx, const unsigned short* __restrict__ WtPr,
            const float* __restrict__ bPr, const unsigned int* __restrict__ fbp,
            float* __restrict__ out, int nnz, int ntiles)
{
    __shared__ unsigned short Al[64 * 128];    // 16 KB
    __shared__ int pI[64], vI[64];
    int t = threadIdx.x, lane = t & 63, w = t >> 6;
    int lr = lane & 15, lg = lane >> 4;
    short8 Bf[4][2];
    #pragma unroll
    for (int kc = 0; kc < 4; ++kc) {
        Bf[kc][0] = *(const short8*)(WtPr + (w * 32 + lr) * 128 + kc * 32 + lg * 8);
        Bf[kc][1] = *(const short8*)(WtPr + (w * 32 + lr + 16) * 128 + kc * 32 + lg * 8);
    }
    int c0 = w * 32 + lr, c1 = c0 + 16;
    unsigned int gw = fbp[(size_t)(NP + NV) * 64 + w * 16 + lr];
    float base0 = 0.25f * bPr[c0] + bflo(gw);
    float base1 = 0.25f * bPr[c1] + bfhi(gw);
    const unsigned int* pfp = fbp;
    const unsigned int* vfp = fbp + (size_t)NP * 64;
    for (int tile = blockIdx.x; tile < ntiles; tile += gridDim.x) {
        int e0 = tile * 64;
        int vrows = min(64, nnz - e0);
        {
            const unsigned short* g = ebuf + (size_t)e0 * 128;
            #pragma unroll
            for (int i = 0; i < 4; ++i) {
                int c = i * 256 + t;
                int row = c >> 4, kb = (c & 15) * 16;
                short8 v = ntld8h(g + row * 128 + (c & 15) * 8);
                *(short8*)&Al[((row * 256 + kb) ^ ((row & 7) << 4)) >> 1] = v;
            }
        }
        if (t < 64) pI[t] = (t < vrows) ? point_idx[e0 + t] : 0;
        else if (t < 128) { int u = t - 64; vI[u] = (u < vrows) ? view_idx[e0 + u] : 0; }
        __syncthreads();
        f32x4 acc[4][2] = {};
        #pragma unroll
        for (int kc = 0; kc < 4; ++kc) {
            int kb = kc * 64 + lg * 16;
            #pragma unroll
            for (int m = 0; m < 4; ++m) {
                int row = m * 16 + lr;
                short8 a = *(const short8*)&Al[((row * 256 + kb) ^ ((row & 7) << 4)) >> 1];
                acc[m][0] = __builtin_amdgcn_mfma_f32_16x16x32_bf16(a, Bf[kc][0], acc[m][0], 0, 0, 0);
                acc[m][1] = __builtin_amdgcn_mfma_f32_16x16x32_bf16(a, Bf[kc][1], acc[m][1], 0, 0, 0);
            }
        }
        #pragma unroll
        for (int m = 0; m < 4; ++m)
            #pragma unroll
            for (int r = 0; r < 4; ++r) {
                int row = m * 16 + lg * 4 + r;
                if (row < vrows) {
                    int p = pI[row], vv = vI[row];
                    unsigned int pu = pfp[(size_t)p * 64 + w * 16 + lr];
                    unsigned int vu = vfp[(size_t)vv * 64 + w * 16 + lr];
                    size_t o = (size_t)(e0 + row) * D;
                    ntst(&out[o + c0], acc[m][0][r] * 0.25f + base0 + bflo(pu) + bflo(vu));
                    ntst(&out[o + c1], acc[m][1][r] * 0.25f + base1 + bfhi(pu) + bfhi(vu));
                }
            }
        __syncthreads();   // protect Al/pI/vI before next tile
    }
}

extern "C" void kernel_launch(void* const* d_in, const int* in_sizes, int n_in,
                              void* d_out, int out_size, void* d_ws, size_t ws_size,
                              hipStream_t stream)
{
    const float* values    = (const float*)d_in[0];
    const int*   view_idx  = (const int*)d_in[1];
    const int*   point_idx = (const int*)d_in[2];
    const float* W_sp   = (const float*)d_in[5];
    const float* b_sp   = (const float*)d_in[6];
    const float* W_view = (const float*)d_in[7];
    const float* b_view = (const float*)d_in[8];
    const float* W_glob = (const float*)d_in[9];
    const float* b_glob = (const float*)d_in[10];
    const float* W_proj = (const float*)d_in[11];
    const float* b_proj = (const float*)d_in[12];
    int nnz = in_sizes[1];
    int ntiles128 = (nnz + 127) / 128;
    int ntiles64 = (nnz + 63) / 64;

    // ws: [gs|Cp|Cv](memset) | bsum|bbase|Bp|Bv | vhist | plist|vlist | Wt4 | mbuf | fbp | ebuf
    char* w = (char*)d_ws;
    float* gs = (float*)w;                          w += 128 * 4;
    int* Cp   = (int*)w;                            w += (size_t)NP * 4;
    int* Cv   = (int*)w;                            w += (size_t)NV * 4;
    size_t zero_bytes = (size_t)(w - (char*)d_ws);
    int* bsum = (int*)w;                            w += 64 * 4;
    int* bbase = (int*)w;                           w += 64 * 4;
    int* Bp   = (int*)w;                            w += (size_t)NP * 4;
    int* Bv   = (int*)w;                            w += (size_t)NV * 4;
    int* vhist = (int*)w;                           w += (size_t)NCB * NV * 4;
    int* plist = (int*)w;                           w += (size_t)nnz * 4;
    int* vlist = (int*)w;                           w += (size_t)nnz * 4;
    unsigned short* Wt4 = (unsigned short*)w;       w += (size_t)4 * 16384 * 2;
    unsigned int* mbuf = (unsigned int*)w;          w += (size_t)(NP + NV) * 64 * 4;
    unsigned int* fbp = (unsigned int*)w;           w += (size_t)(NP + NV + 1) * 64 * 4;
    unsigned int* ebuf = (unsigned int*)w;          w += (size_t)ntiles128 * 128 * 64 * 4;

    hipMemsetAsync(d_ws, 0, zero_bytes, stream);

    hipLaunchKernelGGL(k_prep, dim3(4), dim3(256), 0, stream,
                       W_sp, W_view, W_glob, W_proj, Wt4);
    hipLaunchKernelGGL(k_cvt, dim3(2048), dim3(256), 0, stream,
                       values, (uint4*)ebuf, nnz);
    hipLaunchKernelGGL(k_count2, dim3(NCB), dim3(256), 0, stream,
                       view_idx, point_idx, Cp, vhist, nnz);
    hipLaunchKernelGGL(k_vred, dim3(NV / 256), dim3(256), 0, stream, vhist, Cv);
    hipLaunchKernelGGL(k_scanA, dim3(64), dim3(256), 0, stream, Cp, bsum);
    hipLaunchKernelGGL(k_scanB, dim3(1), dim3(256), 0, stream, bsum, bbase, Cv, Bv);
    hipLaunchKernelGGL(k_scanC, dim3(64), dim3(256), 0, stream, Cp, Bp, bbase);
    hipLaunchKernelGGL(k_scatter, dim3(NSB), dim3(256), 0, stream,
                       view_idx, point_idx, Cp, Cv, plist, vlist, nnz);
    hipLaunchKernelGGL(k_psum, dim3(2048), dim3(256), 0, stream,
                       ebuf, plist, Bp, Cp, mbuf);
    hipLaunchKernelGGL(k_vsum, dim3(NV), dim3(512), 0, stream,
                       ebuf, vlist, Bv, Cv, mbuf, gs);
    hipLaunchKernelGGL(k_featgemm, dim3(521), dim3(256), 0, stream,
                       mbuf, Wt4, b_sp, b_view, b_glob, gs, 1.f / (float)nnz, fbp);
    hipLaunchKernelGGL(k_proj, dim3(2048), dim3(256), 0, stream,
                       (const unsigned short*)ebuf, point_idx, view_idx,
                       Wt4 + (size_t)3 * 16384, b_proj, fbp,
                       (float*)d_out, nnz, ntiles64);
}

// Round 16
// 630.025 us; speedup vs baseline: 1.5431x; 1.0325x over previous
//
#include <hip/hip_runtime.h>

#define D 128
#define NP 65536
#define NV 1024
#define NCB 256   // count blocks
#define NSB 256   // scatter blocks

typedef __attribute__((ext_vector_type(8))) short short8;
typedef __attribute__((ext_vector_type(4))) float f32x4;

__device__ __forceinline__ unsigned short f2bf(float x) {
    unsigned int u = __builtin_bit_cast(unsigned int, x);
    u += 0x7FFFu + ((u >> 16) & 1u);          // round-to-nearest-even
    return (unsigned short)(u >> 16);
}
__device__ __forceinline__ unsigned int pack2bf(float a, float b) {
    return (unsigned int)f2bf(a) | ((unsigned int)f2bf(b) << 16);
}
__device__ __forceinline__ float bflo(unsigned int u) {
    return __builtin_bit_cast(float, u << 16);
}
__device__ __forceinline__ float bfhi(unsigned int u) {
    return __builtin_bit_cast(float, u & 0xFFFF0000u);
}
__device__ __forceinline__ short8 ntld8h(const unsigned short* p) {
    return __builtin_nontemporal_load((const short8*)p);
}

// ---------------- weight prep: W[k][n] f32 -> Wt[n][k] bf16 ----------------
__global__ __launch_bounds__(256)
void k_prep(const float* __restrict__ Wsp, const float* __restrict__ Wvw,
            const float* __restrict__ Wgl, const float* __restrict__ Wpr,
            unsigned short* __restrict__ o)
{
    const float* W = (blockIdx.x == 0) ? Wsp : (blockIdx.x == 1) ? Wvw
                   : (blockIdx.x == 2) ? Wgl : Wpr;
    unsigned short* Wt = o + (size_t)blockIdx.x * 16384;
    for (int c = threadIdx.x; c < 2048; c += 256) {
        int n = c >> 4, kb = (c & 15) * 8;
        unsigned int p[4];
        #pragma unroll
        for (int j = 0; j < 4; ++j)
            p[j] = pack2bf(W[(kb + 2 * j) * D + n], W[(kb + 2 * j + 1) * D + n]);
        *(short8*)(Wt + n * 128 + kb) = *(short8*)p;
    }
}

// ---------------- pure f32 -> bf16 entry-order copy (no atomics) ----------------
__global__ __launch_bounds__(256)
void k_cvt(const float* __restrict__ values, uint4* __restrict__ ebuf4, int nnz)
{
    size_t total = (size_t)nnz * 16;
    size_t step = (size_t)gridDim.x * 1024;
    for (size_t base = (size_t)blockIdx.x * 1024; base < total; base += step) {
        size_t i0 = base + threadIdx.x;
        f32x4 a[4], b[4];
        #pragma unroll
        for (int q = 0; q < 4; ++q) {
            size_t i = i0 + (size_t)q * 256;
            if (i < total) {
                const float* src = values + i * 8;
                a[q] = *(const f32x4*)src;
                b[q] = *(const f32x4*)(src + 4);
            }
        }
        #pragma unroll
        for (int q = 0; q < 4; ++q) {
            size_t i = i0 + (size_t)q * 256;
            if (i < total) {
                uint4 o;
                o.x = pack2bf(a[q][0], a[q][1]); o.y = pack2bf(a[q][2], a[q][3]);
                o.z = pack2bf(b[q][0], b[q][1]); o.w = pack2bf(b[q][2], b[q][3]);
                ebuf4[i] = o;
            }
        }
    }
}

// ---------------- counts: LDS-aggregated view histogram + direct point atomics ----------------
__global__ __launch_bounds__(256)
void k_count2(const int* __restrict__ vi, const int* __restrict__ pi,
              int* __restrict__ cp, int* __restrict__ vhist, int nnz)
{
    __shared__ int h[NV];
    int t = threadIdx.x;
    #pragma unroll
    for (int i = t; i < NV; i += 256) h[i] = 0;
    __syncthreads();
    int i0 = blockIdx.x * 256 + t;
    int stride = gridDim.x * 256;
    for (int e = i0; e < nnz; e += stride) {
        atomicAdd(&cp[pi[e]], 1);
        atomicAdd(&h[vi[e]], 1);
    }
    __syncthreads();
    #pragma unroll
    for (int i = t; i < NV; i += 256) vhist[blockIdx.x * NV + i] = h[i];
}

// reduce per-block view partials -> Cv (no atomics). grid 4 x 256
__global__ __launch_bounds__(256)
void k_vred(const int* __restrict__ vhist, int* __restrict__ cv)
{
    int b = blockIdx.x * 256 + threadIdx.x;   // bin
    int s = 0;
    for (int p = 0; p < NCB; ++p) s += vhist[p * NV + b];
    cv[b] = s;
}

// ---------------- scans ----------------
__global__ __launch_bounds__(256)
void k_scanA(const int* __restrict__ cp, int* __restrict__ bsum)
{
    __shared__ int l[256];
    int t = threadIdx.x;
    int4 c = ((const int4*)cp)[blockIdx.x * 256 + t];
    l[t] = c.x + c.y + c.z + c.w;
    __syncthreads();
    for (int d = 128; d > 0; d >>= 1) {
        if (t < d) l[t] += l[t + d];
        __syncthreads();
    }
    if (t == 0) bsum[blockIdx.x] = l[0];
}

__global__ __launch_bounds__(256)
void k_scanB(const int* __restrict__ bsum, int* __restrict__ bbase,
             int* __restrict__ cv, int* __restrict__ bv)
{
    __shared__ int l[256];
    int t = threadIdx.x;
    int own = (t < 64) ? bsum[t] : 0;
    l[t] = own;
    __syncthreads();
    for (int d = 1; d < 64; d <<= 1) {
        int u = (t >= d && t < 64) ? l[t - d] : 0;
        __syncthreads();
        if (t < 64) l[t] += u;
        __syncthreads();
    }
    if (t < 64) bbase[t] = l[t] - own;
    __syncthreads();
    int4 c = ((const int4*)cv)[t];
    int s4 = c.x + c.y + c.z + c.w;
    l[t] = s4;
    __syncthreads();
    for (int d = 1; d < 256; d <<= 1) {
        int u = (t >= d) ? l[t - d] : 0;
        __syncthreads();
        l[t] += u;
        __syncthreads();
    }
    int ex = l[t] - s4;
    int4 o; o.x = ex; o.y = ex + c.x; o.z = o.y + c.y; o.w = o.z + c.z;
    ((int4*)bv)[t] = o;
    ((int4*)cv)[t] = o;
}

__global__ __launch_bounds__(256)
void k_scanC(int* __restrict__ cp, int* __restrict__ bp, const int* __restrict__ bbase)
{
    __shared__ int l[256];
    int t = threadIdx.x;
    int i = blockIdx.x * 256 + t;
    int4 c = ((const int4*)cp)[i];
    int s4 = c.x + c.y + c.z + c.w;
    l[t] = s4;
    __syncthreads();
    for (int d = 1; d < 256; d <<= 1) {
        int u = (t >= d) ? l[t - d] : 0;
        __syncthreads();
        l[t] += u;
        __syncthreads();
    }
    int ex = l[t] - s4 + bbase[blockIdx.x];
    int4 o; o.x = ex; o.y = ex + c.x; o.z = o.y + c.y; o.w = o.z + c.z;
    ((int4*)bp)[i] = o;
    ((int4*)cp)[i] = o;
}

// ---------------- scatter: two-level binned views, direct points ----------------
__global__ __launch_bounds__(256)
void k_scatter(const int* __restrict__ vi, const int* __restrict__ pi,
               int* __restrict__ curp, int* __restrict__ curv,
               int* __restrict__ plist, int* __restrict__ vlist, int nnz)
{
    __shared__ int h[NV];
    __shared__ int hbase[NV];
    int t = threadIdx.x;
    #pragma unroll
    for (int i = t; i < NV; i += 256) h[i] = 0;
    __syncthreads();
    int chunk = (nnz + gridDim.x - 1) / gridDim.x;   // <= 4096 for 256 blocks
    int s = blockIdx.x * chunk;
    int e = min(nnz, s + chunk);
    int v_[16], lr_[16];
    #pragma unroll
    for (int k = 0; k < 16; ++k) {
        int idx = s + k * 256 + t;
        v_[k] = -1; lr_[k] = 0;
        if (idx < e) {
            int v = vi[idx];
            v_[k] = v;
            lr_[k] = atomicAdd(&h[v], 1);
            int sp = atomicAdd(&curp[pi[idx]], 1);
            plist[sp] = idx;
        }
    }
    __syncthreads();
    #pragma unroll
    for (int i = t; i < NV; i += 256) {
        int c = h[i];
        hbase[i] = c ? atomicAdd(&curv[i], c) : 0;
    }
    __syncthreads();
    #pragma unroll
    for (int k = 0; k < 16; ++k) {
        int idx = s + k * 256 + t;
        if (idx < e) vlist[hbase[v_[k]] + lr_[k]] = idx;
    }
}

// ---------------- point sums: masked 16-deep gather from ebuf ----------------
__global__ __launch_bounds__(256)
void k_psum(const unsigned int* __restrict__ ebuf, const int* __restrict__ plist,
            const int* __restrict__ pbase, const int* __restrict__ pend,
            unsigned int* __restrict__ mbuf)
{
    int lane = threadIdx.x & 63, wv = threadIdx.x >> 6;
    int wave = blockIdx.x * 4 + wv, nw = gridDim.x * 4;
    for (int pt = wave; pt < NP; pt += nw) {
        int s = pbase[pt], e = pend[pt];
        float s0 = 0.f, s1 = 0.f;
        for (int b = s; b < e; b += 64) {
            int n = min(64, e - b);
            int idx = plist[b + min(lane, n - 1)];
            for (int j = 0; j < n; j += 16) {
                unsigned int u[16];
                #pragma unroll
                for (int q = 0; q < 16; ++q) {
                    int jj = (j + q < n) ? (j + q) : (n - 1);
                    int ent = __builtin_amdgcn_readlane(idx, jj);
                    u[q] = ebuf[(size_t)ent * 64 + lane];
                }
                #pragma unroll
                for (int q = 0; q < 16; ++q)
                    if (j + q < n) { s0 += bflo(u[q]); s1 += bfhi(u[q]); }
            }
        }
        float inv = 1.f / fmaxf((float)(e - s), 1.f);
        mbuf[(size_t)pt * 64 + lane] = pack2bf(s0 * inv, s1 * inv);
    }
}

// ---------------- view sums: 8 waves/block, 16 rows in flight ----------------
__global__ __launch_bounds__(512)
void k_vsum(const unsigned int* __restrict__ ebuf, const int* __restrict__ vlist,
            const int* __restrict__ vbase, const int* __restrict__ vend,
            unsigned int* __restrict__ mbuf, float* __restrict__ gs)
{
    __shared__ float2 red[8][64];
    int lane = threadIdx.x & 63, wv = threadIdx.x >> 6;
    int v = blockIdx.x;
    int s = vbase[v], e = vend[v];
    float s0 = 0.f, s1 = 0.f;
    for (int b = s + wv * 64; b < e; b += 512) {
        int n = min(64, e - b);
        int idx = vlist[b + min(lane, n - 1)];
        for (int j = 0; j < n; j += 16) {
            unsigned int u[16];
            #pragma unroll
            for (int q = 0; q < 16; ++q) {
                int jj = (j + q < n) ? (j + q) : (n - 1);
                int r = __builtin_amdgcn_readlane(idx, jj);
                u[q] = ebuf[(size_t)r * 64 + lane];
            }
            #pragma unroll
            for (int q = 0; q < 16; ++q)
                if (j + q < n) { s0 += bflo(u[q]); s1 += bfhi(u[q]); }
        }
    }
    red[wv][lane] = make_float2(s0, s1);
    __syncthreads();
    if (wv == 0) {
        float t0 = 0.f, t1 = 0.f;
        #pragma unroll
        for (int q = 0; q < 8; ++q) { t0 += red[q][lane].x; t1 += red[q][lane].y; }
        atomicAdd(&gs[lane * 2], t0);
        atomicAdd(&gs[lane * 2 + 1], t1);
        float inv = 1.f / fmaxf((float)(e - s), 1.f);
        mbuf[(size_t)(NP + v) * 64 + lane] = pack2bf(t0 * inv, t1 * inv);
    }
}

// ---------------- MFMA tile helpers ----------------
// LDS layout: bf16 [rows][128 k], byte addr = (row*256 + k*2) ^ ((row&7)<<4)
__device__ __forceinline__ void stage_bf16(const unsigned short* __restrict__ g,
                                           unsigned short* lds, int t)
{
    #pragma unroll
    for (int i = 0; i < 8; ++i) {
        int c = i * 256 + t;
        int row = c >> 4, kb = (c & 15) * 16;
        short8 v = *(const short8*)(g + row * 128 + (c & 15) * 8);
        *(short8*)&lds[((row * 256 + kb) ^ ((row & 7) << 4)) >> 1] = v;
    }
}

__device__ __forceinline__ void mfma_tile(const unsigned short* Al, const unsigned short* Bl,
                                          int lane, int w, f32x4 acc[8][2])
{
    int lr = lane & 15, lg = lane >> 4;
    #pragma unroll
    for (int kc = 0; kc < 4; ++kc) {
        int kb = kc * 64 + lg * 16;
        int bn0 = w * 32 + lr, bn1 = bn0 + 16;
        short8 b0 = *(const short8*)&Bl[((bn0 * 256 + kb) ^ ((bn0 & 7) << 4)) >> 1];
        short8 b1 = *(const short8*)&Bl[((bn1 * 256 + kb) ^ ((bn1 & 7) << 4)) >> 1];
        #pragma unroll
        for (int m = 0; m < 8; ++m) {
            int row = m * 16 + lr;
            short8 a = *(const short8*)&Al[((row * 256 + kb) ^ ((row & 7) << 4)) >> 1];
            acc[m][0] = __builtin_amdgcn_mfma_f32_16x16x32_bf16(a, b0, acc[m][0], 0, 0, 0);
            acc[m][1] = __builtin_amdgcn_mfma_f32_16x16x32_bf16(a, b1, acc[m][1], 0, 0, 0);
        }
    }
}

// ---------------- feature GEMM -> packed (c,c+16) uint rows ----------------
__global__ __launch_bounds__(256)
void k_featgemm(const unsigned int* __restrict__ mbuf, const unsigned short* __restrict__ Wt4,
                const float* __restrict__ bSp, const float* __restrict__ bVw,
                const float* __restrict__ bGl, const float* __restrict__ gs,
                float inv_nnz, unsigned int* __restrict__ fbp)
{
    __shared__ unsigned short Al[128 * 128];
    __shared__ unsigned short Bl[128 * 128];
    int t = threadIdx.x;
    int tile = blockIdx.x;   // 0..520
    const unsigned short* Wt; const float* bias; int rowbase; int vrows = 128;
    if (tile < 512)      { Wt = Wt4;             bias = bSp; rowbase = tile * 128; }
    else if (tile < 520) { Wt = Wt4 + 16384;     bias = bVw; rowbase = NP + (tile - 512) * 128; }
    else                 { Wt = Wt4 + 2 * 16384; bias = bGl; rowbase = NP + NV; vrows = 1; }
    stage_bf16(Wt, Bl, t);
    if (tile < 520) {
        stage_bf16((const unsigned short*)(mbuf + (size_t)rowbase * 64), Al, t);
    } else {
        #pragma unroll
        for (int i = 0; i < 8; ++i) {
            int c = i * 256 + t;
            int row = c >> 4, cb = (c & 15) * 8;
            unsigned int p[4] = {0u, 0u, 0u, 0u};
            if (row == 0) {
                #pragma unroll
                for (int j = 0; j < 4; ++j)
                    p[j] = pack2bf(gs[cb + 2 * j] * inv_nnz, gs[cb + 2 * j + 1] * inv_nnz);
            }
            *(short8*)&Al[((row * 256 + cb * 2) ^ ((row & 7) << 4)) >> 1] = *(short8*)p;
        }
    }
    __syncthreads();
    f32x4 acc[8][2] = {};
    int lane = t & 63, w = t >> 6;
    mfma_tile(Al, Bl, lane, w, acc);
    int lr = lane & 15, lg = lane >> 4;
    int c0 = w * 32 + lr, c1 = c0 + 16;
    float bb0 = 0.25f * bias[c0], bb1 = 0.25f * bias[c1];
    #pragma unroll
    for (int m = 0; m < 8; ++m)
        #pragma unroll
        for (int r = 0; r < 4; ++r) {
            int row = m * 16 + lg * 4 + r;
            if (row < vrows)
                fbp[(size_t)(rowbase + row) * 64 + w * 16 + lr] =
                    pack2bf(acc[m][0][r] * 0.25f + bb0, acc[m][1][r] * 0.25f + bb1);
        }
}

// ---------------- projection: 64-row tiles, feature prefetch before MFMA ----------------
__global__ __launch_bounds__(256)
void k_proj(const unsigned short* __restrict__ ebuf, const int* __restrict__ point_idx,
            const int* __restrict__ view_idx, const unsigned short* __restrict__ WtPr,
            const float* __restrict__ bPr, const unsigned int* __restrict__ fbp,
            float* __restrict__ out, int nnz, int ntiles)
{
    __shared__ unsigned short Al[64 * 128];    // 16 KB
    __shared__ int pI[64], vI[64];
    int t = threadIdx.x, lane = t & 63, w = t >> 6;
    int lr = lane & 15, lg = lane >> 4;
    short8 Bf[4][2];
    #pragma unroll
    for (int kc = 0; kc < 4; ++kc) {
        Bf[kc][0] = *(const short8*)(WtPr + (w * 32 + lr) * 128 + kc * 32 + lg * 8);
        Bf[kc][1] = *(const short8*)(WtPr + (w * 32 + lr + 16) * 128 + kc * 32 + lg * 8);
    }
    int c0 = w * 32 + lr, c1 = c0 + 16;
    unsigned int gw = fbp[(size_t)(NP + NV) * 64 + w * 16 + lr];
    float base0 = 0.25f * bPr[c0] + bflo(gw);
    float base1 = 0.25f * bPr[c1] + bfhi(gw);
    const unsigned int* pfp = fbp;
    const unsigned int* vfp = fbp + (size_t)NP * 64;
    for (int tile = blockIdx.x; tile < ntiles; tile += gridDim.x) {
        int e0 = tile * 64;
        int vrows = min(64, nnz - e0);
        {
            const unsigned short* g = ebuf + (size_t)e0 * 128;
            #pragma unroll
            for (int i = 0; i < 4; ++i) {
                int c = i * 256 + t;
                int row = c >> 4, kb = (c & 15) * 16;
                short8 v = ntld8h(g + row * 128 + (c & 15) * 8);
                *(short8*)&Al[((row * 256 + kb) ^ ((row & 7) << 4)) >> 1] = v;
            }
        }
        if (t < 64) pI[t] = (t < vrows) ? point_idx[e0 + t] : 0;
        else if (t < 128) { int u = t - 64; vI[u] = (u < vrows) ? view_idx[e0 + u] : 0; }
        __syncthreads();
        // issue feature gathers FIRST — their latency hides under the MFMA block
        unsigned int puR[4][4], vuR[4][4];
        #pragma unroll
        for (int m = 0; m < 4; ++m)
            #pragma unroll
            for (int r = 0; r < 4; ++r) {
                int row = m * 16 + lg * 4 + r;
                puR[m][r] = pfp[(size_t)pI[row] * 64 + w * 16 + lr];
                vuR[m][r] = vfp[(size_t)vI[row] * 64 + w * 16 + lr];
            }
        f32x4 acc[4][2] = {};
        #pragma unroll
        for (int kc = 0; kc < 4; ++kc) {
            int kb = kc * 64 + lg * 16;
            #pragma unroll
            for (int m = 0; m < 4; ++m) {
                int row = m * 16 + lr;
                short8 a = *(const short8*)&Al[((row * 256 + kb) ^ ((row & 7) << 4)) >> 1];
                acc[m][0] = __builtin_amdgcn_mfma_f32_16x16x32_bf16(a, Bf[kc][0], acc[m][0], 0, 0, 0);
                acc[m][1] = __builtin_amdgcn_mfma_f32_16x16x32_bf16(a, Bf[kc][1], acc[m][1], 0, 0, 0);
            }
        }
        #pragma unroll
        for (int m = 0; m < 4; ++m)
            #pragma unroll
            for (int r = 0; r < 4; ++r) {
                int row = m * 16 + lg * 4 + r;
                if (row < vrows) {
                    size_t o = (size_t)(e0 + row) * D;
                    out[o + c0] = acc[m][0][r] * 0.25f + base0 + bflo(puR[m][r]) + bflo(vuR[m][r]);
                    out[o + c1] = acc[m][1][r] * 0.25f + base1 + bfhi(puR[m][r]) + bfhi(vuR[m][r]);
                }
            }
        __syncthreads();   // protect Al/pI/vI before next tile
    }
}

extern "C" void kernel_launch(void* const* d_in, const int* in_sizes, int n_in,
                              void* d_out, int out_size, void* d_ws, size_t ws_size,
                              hipStream_t stream)
{
    const float* values    = (const float*)d_in[0];
    const int*   view_idx  = (const int*)d_in[1];
    const int*   point_idx = (const int*)d_in[2];
    const float* W_sp   = (const float*)d_in[5];
    const float* b_sp   = (const float*)d_in[6];
    const float* W_view = (const float*)d_in[7];
    const float* b_view = (const float*)d_in[8];
    const float* W_glob = (const float*)d_in[9];
    const float* b_glob = (const float*)d_in[10];
    const float* W_proj = (const float*)d_in[11];
    const float* b_proj = (const float*)d_in[12];
    int nnz = in_sizes[1];
    int ntiles128 = (nnz + 127) / 128;
    int ntiles64 = (nnz + 63) / 64;

    // ws: [gs|Cp|Cv](memset) | bsum|bbase|Bp|Bv | vhist | plist|vlist | Wt4 | mbuf | fbp | ebuf
    char* w = (char*)d_ws;
    float* gs = (float*)w;                          w += 128 * 4;
    int* Cp   = (int*)w;                            w += (size_t)NP * 4;
    int* Cv   = (int*)w;                            w += (size_t)NV * 4;
    size_t zero_bytes = (size_t)(w - (char*)d_ws);
    int* bsum = (int*)w;                            w += 64 * 4;
    int* bbase = (int*)w;                           w += 64 * 4;
    int* Bp   = (int*)w;                            w += (size_t)NP * 4;
    int* Bv   = (int*)w;                            w += (size_t)NV * 4;
    int* vhist = (int*)w;                           w += (size_t)NCB * NV * 4;
    int* plist = (int*)w;                           w += (size_t)nnz * 4;
    int* vlist = (int*)w;                           w += (size_t)nnz * 4;
    unsigned short* Wt4 = (unsigned short*)w;       w += (size_t)4 * 16384 * 2;
    unsigned int* mbuf = (unsigned int*)w;          w += (size_t)(NP + NV) * 64 * 4;
    unsigned int* fbp = (unsigned int*)w;           w += (size_t)(NP + NV + 1) * 64 * 4;
    unsigned int* ebuf = (unsigned int*)w;          w += (size_t)ntiles128 * 128 * 64 * 4;

    hipMemsetAsync(d_ws, 0, zero_bytes, stream);

    hipLaunchKernelGGL(k_prep, dim3(4), dim3(256), 0, stream,
                       W_sp, W_view, W_glob, W_proj, Wt4);
    hipLaunchKernelGGL(k_cvt, dim3(2048), dim3(256), 0, stream,
                       values, (uint4*)ebuf, nnz);
    hipLaunchKernelGGL(k_count2, dim3(NCB), dim3(256), 0, stream,
                       view_idx, point_idx, Cp, vhist, nnz);
    hipLaunchKernelGGL(k_vred, dim3(NV / 256), dim3(256), 0, stream, vhist, Cv);
    hipLaunchKernelGGL(k_scanA, dim3(64), dim3(256), 0, stream, Cp, bsum);
    hipLaunchKernelGGL(k_scanB, dim3(1), dim3(256), 0, stream, bsum, bbase, Cv, Bv);
    hipLaunchKernelGGL(k_scanC, dim3(64), dim3(256), 0, stream, Cp, Bp, bbase);
    hipLaunchKernelGGL(k_scatter, dim3(NSB), dim3(256), 0, stream,
                       view_idx, point_idx, Cp, Cv, plist, vlist, nnz);
    hipLaunchKernelGGL(k_psum, dim3(2048), dim3(256), 0, stream,
                       ebuf, plist, Bp, Cp, mbuf);
    hipLaunchKernelGGL(k_vsum, dim3(NV), dim3(512), 0, stream,
                       ebuf, vlist, Bv, Cv, mbuf, gs);
    hipLaunchKernelGGL(k_featgemm, dim3(521), dim3(256), 0, stream,
                       mbuf, Wt4, b_sp, b_view, b_glob, gs, 1.f / (float)nnz, fbp);
    hipLaunchKernelGGL(k_proj, dim3(2048), dim3(256), 0, stream,
                       (const unsigned short*)ebuf, point_idx, view_idx,
                       Wt4 + (size_t)3 * 16384, b_proj, fbp,
                       (float*)d_out, nnz, ntiles64);
}